// Round 3
// 633.707 us; speedup vs baseline: 1.0560x; 1.0560x over previous
//
#include <hip/hip_runtime.h>
#include <cmath>
#include <cfloat>
#include <climits>

#define NFEAT 20000
#define DDIM 256
#define KDIM 64
#define SEGN 32    // columns per segment; 20000 = 625 * 32 exactly (no tail)
#define NSEG 625
#define SEGP 640   // padded leading dim for [d][s] arrays

// log2-domain constants. Everything (acc, lse, L, gumbel, z) is carried in
// log2 units; orderings are identical to the ln-domain formulation since
// every quantity is a positive multiple (1/ln2) of its ln-domain twin.
#define LOG2E 1.4426950408889634
#define INVT (1.0 / 9.9999)              // multiply instead of f64 divide
#define LOG2_10 3.3219280948873623
#define G2C 0.5287663729448976           // -log2(ln 2)
#define LO2 -23.253496664211536          // log2(1e-7)
#define HI2 -1.4426951130237154e-7       // log2(0.9999999)

// ---------------------------------------------------------------------------
// Branch-free fast f64 exp2/log2. |rel err| ~1e-13 — 6+ orders below the
// decision gaps (the f32 reference matching true ordering implies gaps
// >~1e-6). No tables, no edge cases: inputs are guaranteed normal, and
// exp2 args are in [-3, 6] (softmax logits / z scores only).
// Deterministic => bitwise-consistent between k_seg and the repair path.
// ---------------------------------------------------------------------------
__device__ __forceinline__ double fexp2(double x) {
  const double nd = rint(x);
  const double y = (x - nd) * 0.6931471805599453;  // r*ln2, |y| <= 0.3466
  double p = 1.0 / 3628800.0;
  p = fma(p, y, 1.0 / 362880.0);
  p = fma(p, y, 1.0 / 40320.0);
  p = fma(p, y, 1.0 / 5040.0);
  p = fma(p, y, 1.0 / 720.0);
  p = fma(p, y, 1.0 / 120.0);
  p = fma(p, y, 1.0 / 24.0);
  p = fma(p, y, 1.0 / 6.0);
  p = fma(p, y, 0.5);
  p = fma(p, y, 1.0);
  p = fma(p, y, 1.0);
  const int n = (int)nd;
  const double sc = __longlong_as_double((long long)(n + 1023) << 52);
  return p * sc;
}

__device__ __forceinline__ double flog2(double x) {
  const long long b = __double_as_longlong(x);
  int e = (int)(b >> 52) - 1023;
  double m = __longlong_as_double((b & 0xfffffffffffffLL) | 0x3ff0000000000000LL);
  if (m > 1.4142135623730951) { m *= 0.5; e += 1; }  // cndmask, no branch
  const double t = (m - 1.0) / (m + 1.0);            // |t| <= 0.1716
  const double w = t * t;
  double p = 1.0 / 13.0;
  p = fma(p, w, 1.0 / 11.0);
  p = fma(p, w, 1.0 / 9.0);
  p = fma(p, w, 1.0 / 7.0);
  p = fma(p, w, 1.0 / 5.0);
  p = fma(p, w, 1.0 / 3.0);
  p = fma(p, w, 1.0);
  return fma((2.0 * LOG2E) * t, p, (double)e);
}

// ---------------------------------------------------------------------------
// Shared post-dot z computation (bitwise-identical in k_seg and repair path).
// z2 = (log2(10) + clamp(L2) + g2) / temp, g2 = -log2(-log2 u) - log2(ln2)
// ---------------------------------------------------------------------------
__device__ __forceinline__ double z2_post(double L2raw, float uu) {
  const double L2 = fmin(fmax(L2raw, LO2), HI2);
  const double t = -flog2((double)uu);   // t in (1.4e-7, 23.3)
  const double g2 = G2C - flog2(t);
  return (LOG2_10 + L2 + g2) * INVT;
}

// Recompute z2[d][n] from scratch: same fma chain as k_seg (ascending k,
// first operand = (double)u * LOG2E rounded once — matches ut2 staging).
__device__ __forceinline__ double compute_z2(
    const float* __restrict__ u, const float* __restrict__ W,
    const float* __restrict__ unif, const double* __restrict__ lseN,
    int dd, int n) {
  double acc = 0.0;
  const float* ur = u + (size_t)n * KDIM;
#pragma unroll 8
  for (int k = 0; k < KDIM; ++k)
    acc = fma((double)ur[k] * LOG2E, (double)W[k * DDIM + dd], acc);
  return z2_post(acc - lseN[n], unif[(size_t)dd * NFEAT + n]);
}

// ---------------------------------------------------------------------------
// K1: one block per 32-column segment (625 blocks -> balanced on 256 CUs;
// LDS 48.3 KB/block -> 3 blocks/CU co-resident, no forced register cap).
// Thread d owns output row d. u staged in LDS as f64 pre-scaled by LOG2E
// (no cvt in the inner dot). No softmax max-shift (|acc2| <= ~5).
// Writes segVal/segSum/segCol in [d][s] layout.
// ---------------------------------------------------------------------------
__global__ __launch_bounds__(256) void k_seg(
    const float* __restrict__ u, const float* __restrict__ W,
    const float* __restrict__ unif, double* __restrict__ lseN,
    double* __restrict__ segVal, double* __restrict__ segSum,
    int* __restrict__ segCol) {
  const int s = blockIdx.x;
  const int n0 = s * SEGN;
  const int d = threadIdx.x;
  const int lane = d & 63, w = d >> 6;

  __shared__ __align__(16) double ut2[SEGN][KDIM];  // 16 KB, (double)u*LOG2E
  __shared__ float unT[SEGN][DDIM];                 // 32 KB
  __shared__ double ssum[4][8];
  __shared__ double lse2s[8];

  for (int i = d; i < SEGN * KDIM; i += 256)
    ut2[i >> 6][i & 63] =
        (double)u[(size_t)(n0 + (i >> 6)) * KDIM + (i & 63)] * LOG2E;
  // stage unif: thread d reads its own row (contiguous 128 B)
  for (int q = 0; q < SEGN; q += 4) {
    const float4 t = *(const float4*)(unif + (size_t)d * NFEAT + n0 + q);
    unT[q + 0][d] = t.x;
    unT[q + 1][d] = t.y;
    unT[q + 2][d] = t.z;
    unT[q + 3][d] = t.w;
  }
  float wcol[KDIM];
#pragma unroll
  for (int k = 0; k < KDIM; ++k) wcol[k] = W[k * DDIM + d];
  __syncthreads();

  double ssl = 0.0;
  double segm = -INFINITY;
  int segc = -1;

  for (int b0 = 0; b0 < SEGN; b0 += 8) {
    double acc[8];
#pragma unroll
    for (int i = 0; i < 8; ++i) acc[i] = 0.0;
#pragma unroll
    for (int k4 = 0; k4 < 16; ++k4) {
      const int kb = k4 * 4;
      const double w0 = (double)wcol[kb + 0], w1 = (double)wcol[kb + 1];
      const double w2 = (double)wcol[kb + 2], w3 = (double)wcol[kb + 3];
#pragma unroll
      for (int i = 0; i < 8; ++i) {
        const double2 ua = *(const double2*)&ut2[b0 + i][kb];
        const double2 ub = *(const double2*)&ut2[b0 + i][kb + 2];
        acc[i] = fma(ua.x, w0, acc[i]);
        acc[i] = fma(ua.y, w1, acc[i]);
        acc[i] = fma(ub.x, w2, acc[i]);
        acc[i] = fma(ub.y, w3, acc[i]);
      }
    }
    // softmax denominator over d (log2 domain; |acc2| <= ~5)
    double sl[8];
#pragma unroll
    for (int i = 0; i < 8; ++i) sl[i] = fexp2(acc[i]);
#pragma unroll
    for (int off = 1; off < 64; off <<= 1)
#pragma unroll
      for (int i = 0; i < 8; ++i) sl[i] += __shfl_xor(sl[i], off, 64);
    if (lane == 0)
#pragma unroll
      for (int i = 0; i < 8; ++i) ssum[w][i] = sl[i];
    __syncthreads();
    if (d < 8) {
      const double tot = ssum[0][d] + ssum[1][d] + ssum[2][d] + ssum[3][d];
      const double lz = flog2(tot);
      lse2s[d] = lz;
      lseN[n0 + b0 + d] = lz;
    }
    __syncthreads();
#pragma unroll 2
    for (int i = 0; i < 8; ++i) {
      const double z2 = z2_post(acc[i] - lse2s[i], unT[b0 + i][d]);
      ssl += fexp2(z2);
      if (z2 > segm) { segm = z2; segc = n0 + b0 + i; }
    }
    __syncthreads();  // protect ssum/lse2s before next batch
  }
  segVal[(size_t)d * SEGP + s] = segm;
  segCol[(size_t)d * SEGP + s] = segc;
  segSum[(size_t)d * SEGP + s] = ssl;
}

// ---------------------------------------------------------------------------
// K2: per row d: logL[d] = log2(sum_s segSum), plus global row best/argmax.
// 256 blocks x 64 lanes, coalesced over the [d][s] layout.
// ---------------------------------------------------------------------------
__global__ __launch_bounds__(64) void k_rowstat(
    const double* __restrict__ segVal, const double* __restrict__ segSum,
    const int* __restrict__ segCol, double* __restrict__ logL,
    double* __restrict__ bestKey, int* __restrict__ bestCol) {
  const int dd = blockIdx.x, lane = threadIdx.x;
  double sum = 0.0, bv = -INFINITY;
  int bc = INT_MAX;
  for (int s = lane; s < NSEG; s += 64) {
    sum += segSum[(size_t)dd * SEGP + s];
    double v = segVal[(size_t)dd * SEGP + s];
    int c = segCol[(size_t)dd * SEGP + s];
    if (c >= 0 && (v > bv || (v == bv && c < bc))) { bv = v; bc = c; }
  }
#pragma unroll
  for (int off = 32; off > 0; off >>= 1) {
    sum += __shfl_xor(sum, off, 64);
    double ov = __shfl_xor(bv, off, 64);
    int oc = __shfl_xor(bc, off, 64);
    if (ov > bv || (ov == bv && oc < bc)) { bv = ov; bc = oc; }
  }
  if (lane == 0) {
    double lL = flog2(sum);
    logL[dd] = lL;
    bestKey[dd] = bv - lL;
    bestCol[dd] = bc;
  }
}

// ---------------------------------------------------------------------------
// K3: batched lazy greedy. Rank-sort 256 rows by key, then commit in sorted
// order 64 at a time; conflicts (suppressed/dup col) trigger wave-parallel
// repair + sorted re-insertion. Expected conflicts ~3 total. Both while
// loops carry hard guards: a bug degrades to a wrong answer, never a hang.
// ---------------------------------------------------------------------------
__global__ __launch_bounds__(64) void k_greedy(
    const float* __restrict__ u, const float* __restrict__ W,
    const float* __restrict__ unif, const double* __restrict__ lseN,
    double* __restrict__ segVal, int* __restrict__ segCol,
    const double* __restrict__ logL, const double* __restrict__ bestKey,
    const int* __restrict__ bestCol, int* __restrict__ sel) {
  const int lane = threadIdx.x;
  __shared__ double kk[DDIM], sk[DDIM];
  __shared__ int sr[DDIM], sc[DDIM], selL[DDIM];
  __shared__ unsigned int supp[NFEAT / 32];
  for (int i = lane; i < NFEAT / 32; i += 64) supp[i] = 0u;

  double myk[4];
  int myc[4];
#pragma unroll
  for (int i = 0; i < 4; ++i) {
    int dd = lane + 64 * i;
    myk[i] = bestKey[dd];
    myc[i] = bestCol[dd];
    kk[dd] = myk[i];
  }
  __syncthreads();
  // rank sort (descending key, tie -> smaller row)
#pragma unroll
  for (int i = 0; i < 4; ++i) {
    int dd = lane + 64 * i;
    int rk = 0;
#pragma unroll 4
    for (int j = 0; j < DDIM; ++j) {
      double kj = kk[j];
      if (kj > myk[i] || (kj == myk[i] && j < dd)) ++rk;
    }
    sk[rk] = myk[i];
    sr[rk] = dd;
    sc[rk] = myc[i];
  }
  __syncthreads();

  int pos = 0;
  for (int guard = 0; guard < 4 * DDIM && pos < DDIM; ++guard) {
    const int p = pos + lane;
    const bool valid = p < DDIM;
    int r = -1, c = -1000000 - lane;  // unique negatives: no accidental dups
    if (valid) { r = sr[p]; c = sc[p]; }
    bool conf = !valid;
    if (valid) conf = (supp[c >> 5] >> (c & 31)) & 1u;
    bool dup = false;
#pragma unroll
    for (int j = 0; j < 63; ++j) {
      int cj = __shfl(c, j, 64);
      if (j < lane && cj == c) dup = true;
    }
    if (valid && dup) conf = true;
    unsigned long long bm = __ballot(conf);
    int fc = bm ? (__ffsll(bm) - 1) : 64;
    if (lane < fc) {
      selL[r] = c;
      atomicOr(&supp[c >> 5], 1u << (c & 31));
    }
    __syncthreads();
    pos += fc;
    if (fc < 64 && pos < DDIM) {
      const int rr = sr[pos];
      // wave-parallel repair of row rr
      double pbv = -INFINITY;
      int pbc = INT_MAX;
      int stale[10];
      int scnt = 0;
#pragma unroll
      for (int i2 = 0; i2 < 10; ++i2) {
        int s2 = lane + 64 * i2;
        if (s2 < NSEG) {
          double v = segVal[(size_t)rr * SEGP + s2];
          int cc = segCol[(size_t)rr * SEGP + s2];
          if (cc >= 0) {
            if ((supp[cc >> 5] >> (cc & 31)) & 1u) stale[scnt++] = s2;
            else if (v > pbv || (v == pbv && cc < pbc)) { pbv = v; pbc = cc; }
          }
        }
      }
      unsigned long long sm2 = __ballot(scnt > 0);
      for (int g2 = 0; g2 < NSEG + 4 && sm2; ++g2) {
        int src = __ffsll(sm2) - 1;
        int cand = (scnt > 0) ? stale[scnt - 1] : 0;
        int s2 = __shfl(cand, src, 64);
        if (lane == src) --scnt;
        int ccol = s2 * SEGN + lane;
        double zv = -INFINITY;
        if (lane < SEGN && !((supp[ccol >> 5] >> (ccol & 31)) & 1u))
          zv = compute_z2(u, W, unif, lseN, rr, ccol);
        int zc = (zv == -INFINITY) ? INT_MAX : ccol;
#pragma unroll
        for (int off = 32; off > 0; off >>= 1) {
          double ov = __shfl_xor(zv, off, 64);
          int oc = __shfl_xor(zc, off, 64);
          if (ov > zv || (ov == zv && oc < zc)) { zv = ov; zc = oc; }
        }
        if (lane == 0) {
          segVal[(size_t)rr * SEGP + s2] = (zc == INT_MAX) ? -INFINITY : zv;
          segCol[(size_t)rr * SEGP + s2] = (zc == INT_MAX) ? -1 : zc;
        }
        if (zc != INT_MAX && (zv > pbv || (zv == pbv && zc < pbc))) {
          pbv = zv;
          pbc = zc;
        }
        sm2 = __ballot(scnt > 0);
      }
#pragma unroll
      for (int off = 32; off > 0; off >>= 1) {
        double ov = __shfl_xor(pbv, off, 64);
        int oc = __shfl_xor(pbc, off, 64);
        if (ov > pbv || (ov == pbv && oc < pbc)) { pbv = ov; pbc = oc; }
      }
      const double knew = pbv - logL[rr];
      const int cn = pbc;
      // count entries that must stay ahead of the repaired one
      int cnt = 0;
      for (int q = pos + 1 + lane; q < DDIM; q += 64) {
        double kq = sk[q];
        int rq = sr[q];
        if (kq > knew || (kq == knew && rq < rr)) ++cnt;
      }
#pragma unroll
      for (int off = 32; off > 0; off >>= 1) cnt += __shfl_xor(cnt, off, 64);
      // shift entries pos+1 .. pos+cnt left by one, insert at pos+cnt
      for (int q0 = pos + 1; q0 <= pos + cnt; q0 += 64) {
        int q = q0 + lane;
        double tk = 0.0;
        int tr = 0, tc = 0;
        bool v2 = q <= pos + cnt;
        if (v2) { tk = sk[q]; tr = sr[q]; tc = sc[q]; }
        __syncthreads();
        if (v2) { sk[q - 1] = tk; sr[q - 1] = tr; sc[q - 1] = tc; }
        __syncthreads();
      }
      if (lane == 0) { sk[pos + cnt] = knew; sr[pos + cnt] = rr; sc[pos + cnt] = cn; }
      __syncthreads();
    }
  }
#pragma unroll
  for (int i = 0; i < 4; ++i) sel[lane + 64 * i] = selL[lane + 64 * i];
}

// ---------------------------------------------------------------------------
// K4: Y[b,d] = X[b, sel[d]] for rows b = 1..4095 (sel in out row 0).
// ---------------------------------------------------------------------------
__global__ __launch_bounds__(256) void k_gather(const float* __restrict__ X,
                                                float* out) {
  const int dd = threadIdx.x;
  const size_t b = (size_t)blockIdx.x + 1;
  const int y = __float_as_int(out[dd]);
  out[b * DDIM + dd] = X[b * NFEAT + y];
}

// K5: row 0 (reads sel from its own slot, then overwrites it).
__global__ __launch_bounds__(256) void k_row0(const float* __restrict__ X,
                                              float* out) {
  const int dd = threadIdx.x;
  const int y = __float_as_int(out[dd]);
  const float v = X[y];
  out[dd] = v;
}

extern "C" void kernel_launch(void* const* d_in, const int* in_sizes, int n_in,
                              void* d_out, int out_size, void* d_ws,
                              size_t ws_size, hipStream_t stream) {
  (void)in_sizes; (void)n_in; (void)d_ws; (void)ws_size; (void)out_size;
  const float* X = (const float*)d_in[0];
  const float* u = (const float*)d_in[1];
  const float* W = (const float*)d_in[2];
  const float* unif = (const float*)d_in[3];

  // Scratch lives inside d_out (4 MB): rows >= 1 are dead until k_gather.
  char* ob = (char*)d_out;
  int* sel = (int*)ob;                       // [0, 1024)
  double* lseN = (double*)(ob + 1024);       // 160000 B -> 161024
  double* logL = (double*)(ob + 161024);     // 2048 B -> 163072
  double* bestKey = (double*)(ob + 163072);  // 2048 B -> 165120
  int* bestCol = (int*)(ob + 165120);        // 1024 B -> 166144
  double* segVal = (double*)(ob + 166144);   // 256*640*8 = 1310720 -> 1476864
  double* segSum = (double*)(ob + 1476864);  // 1310720 -> 2787584
  int* segCol = (int*)(ob + 2787584);        // 655360 -> 3442944 (< 4194304)

  k_seg<<<NSEG, 256, 0, stream>>>(u, W, unif, lseN, segVal, segSum, segCol);
  k_rowstat<<<DDIM, 64, 0, stream>>>(segVal, segSum, segCol, logL, bestKey,
                                     bestCol);
  k_greedy<<<1, 64, 0, stream>>>(u, W, unif, lseN, segVal, segCol, logL,
                                 bestKey, bestCol, sel);
  k_gather<<<4095, 256, 0, stream>>>(X, (float*)d_out);
  k_row0<<<1, 256, 0, stream>>>(X, (float*)d_out);
}

// Round 4
// 623.183 us; speedup vs baseline: 1.0739x; 1.0169x over previous
//
#include <hip/hip_runtime.h>
#include <cmath>
#include <cfloat>
#include <climits>

#define NFEAT 20000
#define DDIM 256
#define KDIM 64
#define SEGN 32    // columns per segment; 20000 = 625 * 32 exactly (no tail)
#define NSEG 625
#define SEGP 640   // padded leading dim for [d][s] arrays

// log2-domain constants. Everything (acc, lse, L, gumbel, z) is carried in
// log2 units; orderings are identical to the ln-domain formulation since
// every quantity is a positive multiple (1/ln2) of its ln-domain twin.
#define LOG2E 1.4426950408889634
#define INVT (1.0 / 9.9999)              // multiply instead of f64 divide
#define LOG2_10 3.3219280948873623
#define G2C 0.5287663729448976           // -log2(ln 2)
#define LO2 -23.253496664211536          // log2(1e-7)
#define HI2 -1.4426951130237154e-7       // log2(0.9999999)

// ---------------------------------------------------------------------------
// Fast f64 reciprocal: v_rcp_f64 seed (>= ~2^-14 accurate) + 2 Newton steps
// -> ~1-2 ulp. Replaces the IEEE divide sequence (div_scale/div_fmas/fixup).
// Shared by k_seg and the repair path => bitwise-consistent.
// ---------------------------------------------------------------------------
__device__ __forceinline__ double frcp(double a) {
  double r;
  asm("v_rcp_f64 %0, %1" : "=v"(r) : "v"(a));
  r = fma(fma(-a, r, 1.0), r, r);
  r = fma(fma(-a, r, 1.0), r, r);
  return r;
}

// ---------------------------------------------------------------------------
// Branch-free fast f64 exp2/log2. |rel err| ~1e-13 — 6+ orders below the
// decision gaps (the f32 reference matching true ordering implies gaps
// >~1e-6). Inputs are guaranteed normal; exp2 args are in [-3, 6].
// Deterministic => bitwise-consistent between k_seg and the repair path.
// ---------------------------------------------------------------------------
__device__ __forceinline__ double fexp2(double x) {
  const double nd = rint(x);
  const double y = (x - nd) * 0.6931471805599453;  // r*ln2, |y| <= 0.3466
  double p = 1.0 / 3628800.0;
  p = fma(p, y, 1.0 / 362880.0);
  p = fma(p, y, 1.0 / 40320.0);
  p = fma(p, y, 1.0 / 5040.0);
  p = fma(p, y, 1.0 / 720.0);
  p = fma(p, y, 1.0 / 120.0);
  p = fma(p, y, 1.0 / 24.0);
  p = fma(p, y, 1.0 / 6.0);
  p = fma(p, y, 0.5);
  p = fma(p, y, 1.0);
  p = fma(p, y, 1.0);
  const int n = (int)nd;
  const double sc = __longlong_as_double((long long)(n + 1023) << 52);
  return p * sc;
}

__device__ __forceinline__ double flog2(double x) {
  const long long b = __double_as_longlong(x);
  int e = (int)(b >> 52) - 1023;
  double m = __longlong_as_double((b & 0xfffffffffffffLL) | 0x3ff0000000000000LL);
  if (m > 1.4142135623730951) { m *= 0.5; e += 1; }  // cndmask, no branch
  const double t = (m - 1.0) * frcp(m + 1.0);        // |t| <= 0.1716
  const double w = t * t;
  double p = 1.0 / 13.0;
  p = fma(p, w, 1.0 / 11.0);
  p = fma(p, w, 1.0 / 9.0);
  p = fma(p, w, 1.0 / 7.0);
  p = fma(p, w, 1.0 / 5.0);
  p = fma(p, w, 1.0 / 3.0);
  p = fma(p, w, 1.0);
  return fma((2.0 * LOG2E) * t, p, (double)e);
}

// ---------------------------------------------------------------------------
// Shared post-dot z computation (bitwise-identical in k_seg and repair path).
// z2 = (log2(10) + clamp(L2) + g2) / temp, g2 = -log2(-log2 u) - log2(ln2)
// ---------------------------------------------------------------------------
__device__ __forceinline__ double z2_post(double L2raw, float uu) {
  const double L2 = fmin(fmax(L2raw, LO2), HI2);
  const double t = -flog2((double)uu);   // t in (2e-7, 23.3)
  const double g2 = G2C - flog2(t);
  return (LOG2_10 + L2 + g2) * INVT;
}

// Recompute z2[d][n] from scratch: same fma chain as k_seg (ascending k,
// first operand = (double)u * LOG2E rounded once — matches ut2 staging).
__device__ __forceinline__ double compute_z2(
    const float* __restrict__ u, const float* __restrict__ W,
    const float* __restrict__ unif, const double* __restrict__ lseN,
    int dd, int n) {
  double acc = 0.0;
  const float* ur = u + (size_t)n * KDIM;
#pragma unroll 8
  for (int k = 0; k < KDIM; ++k)
    acc = fma((double)ur[k] * LOG2E, (double)W[k * DDIM + dd], acc);
  return z2_post(acc - lseN[n], unif[(size_t)dd * NFEAT + n]);
}

// Monotone double -> u64 key (all finite values, both signs).
__device__ __forceinline__ unsigned long long dkey(double v) {
  const long long b = __double_as_longlong(v);
  const unsigned long long ub = (unsigned long long)b;
  return (b < 0) ? ~ub : (ub | 0x8000000000000000ull);
}

// ---------------------------------------------------------------------------
// K0: zero the per-row atomic accumulators (d_out scratch is poisoned
// between iterations).
// ---------------------------------------------------------------------------
__global__ __launch_bounds__(256) void k_init(double* __restrict__ rowSum,
                                              unsigned long long* __restrict__ rowKey) {
  rowSum[threadIdx.x] = 0.0;
  rowKey[threadIdx.x] = 0ull;  // below any real key (keys >= ~4.6e18)
}

// ---------------------------------------------------------------------------
// K1: one block per 32-column segment (625 blocks, 3 blocks/CU co-resident).
// Thread d owns output row d. u staged in LDS as f64 pre-scaled by LOG2E.
// No softmax max-shift (|acc2| <= ~5). Writes segVal/segCol in [d][s]
// layout and folds the old k_rowstat into atomics:
//   rowSum[d]  += sum_n exp2(z2)                  (f64 atomicAdd)
//   rowKey[d] max= (trunc48(segmax), 0xFFFF-col)  (u64 atomicMax)
// trunc48 quantum ~3.6e-15 rel — 8 orders below decision gaps; exact value
// is recovered from segVal in k_greedy's preamble.
// ---------------------------------------------------------------------------
__global__ __launch_bounds__(256) void k_seg(
    const float* __restrict__ u, const float* __restrict__ W,
    const float* __restrict__ unif, double* __restrict__ lseN,
    double* __restrict__ segVal, int* __restrict__ segCol,
    double* __restrict__ rowSum, unsigned long long* __restrict__ rowKey) {
  const int s = blockIdx.x;
  const int n0 = s * SEGN;
  const int d = threadIdx.x;
  const int lane = d & 63, w = d >> 6;

  __shared__ __align__(16) double ut2[SEGN][KDIM];  // 16 KB, (double)u*LOG2E
  __shared__ float unT[SEGN][DDIM];                 // 32 KB
  __shared__ double ssum[4][8];
  __shared__ double lse2s[8];

  for (int i = d; i < SEGN * KDIM; i += 256)
    ut2[i >> 6][i & 63] =
        (double)u[(size_t)(n0 + (i >> 6)) * KDIM + (i & 63)] * LOG2E;
  // stage unif: thread d reads its own row (contiguous 128 B)
  for (int q = 0; q < SEGN; q += 4) {
    const float4 t = *(const float4*)(unif + (size_t)d * NFEAT + n0 + q);
    unT[q + 0][d] = t.x;
    unT[q + 1][d] = t.y;
    unT[q + 2][d] = t.z;
    unT[q + 3][d] = t.w;
  }
  float wcol[KDIM];
#pragma unroll
  for (int k = 0; k < KDIM; ++k) wcol[k] = W[k * DDIM + d];
  __syncthreads();

  double ssl = 0.0;
  double segm = -INFINITY;
  int segc = -1;

  for (int b0 = 0; b0 < SEGN; b0 += 8) {
    double acc[8];
#pragma unroll
    for (int i = 0; i < 8; ++i) acc[i] = 0.0;
#pragma unroll
    for (int k4 = 0; k4 < 16; ++k4) {
      const int kb = k4 * 4;
      const double w0 = (double)wcol[kb + 0], w1 = (double)wcol[kb + 1];
      const double w2 = (double)wcol[kb + 2], w3 = (double)wcol[kb + 3];
#pragma unroll
      for (int i = 0; i < 8; ++i) {
        const double2 ua = *(const double2*)&ut2[b0 + i][kb];
        const double2 ub = *(const double2*)&ut2[b0 + i][kb + 2];
        acc[i] = fma(ua.x, w0, acc[i]);
        acc[i] = fma(ua.y, w1, acc[i]);
        acc[i] = fma(ub.x, w2, acc[i]);
        acc[i] = fma(ub.y, w3, acc[i]);
      }
    }
    // softmax denominator over d (log2 domain; |acc2| <= ~5)
    double sl[8];
#pragma unroll
    for (int i = 0; i < 8; ++i) sl[i] = fexp2(acc[i]);
#pragma unroll
    for (int off = 1; off < 64; off <<= 1)
#pragma unroll
      for (int i = 0; i < 8; ++i) sl[i] += __shfl_xor(sl[i], off, 64);
    if (lane == 0)
#pragma unroll
      for (int i = 0; i < 8; ++i) ssum[w][i] = sl[i];
    __syncthreads();
    if (d < 8) {
      const double tot = ssum[0][d] + ssum[1][d] + ssum[2][d] + ssum[3][d];
      const double lz = flog2(tot);
      lse2s[d] = lz;
      lseN[n0 + b0 + d] = lz;
    }
    __syncthreads();
#pragma unroll 2
    for (int i = 0; i < 8; ++i) {
      const double z2 = z2_post(acc[i] - lse2s[i], unT[b0 + i][d]);
      ssl += fexp2(z2);
      if (z2 > segm) { segm = z2; segc = n0 + b0 + i; }
    }
    __syncthreads();  // protect ssum/lse2s before next batch
  }
  segVal[(size_t)d * SEGP + s] = segm;
  segCol[(size_t)d * SEGP + s] = segc;
  atomicAdd(&rowSum[d], ssl);
  atomicMax(&rowKey[d], (dkey(segm) & 0xFFFFFFFFFFFF0000ull) |
                            (unsigned long long)(0xFFFF - segc));
}

// ---------------------------------------------------------------------------
// K3: batched lazy greedy. Preamble rebuilds exact per-row (bestVal, bestCol,
// logL) from rowKey/rowSum/segVal. Then rank-sort 256 rows by key and commit
// in sorted order 64 at a time; conflicts trigger wave-parallel repair +
// sorted re-insertion. Hard guards: bugs degrade to wrong answer, not hang.
// ---------------------------------------------------------------------------
__global__ __launch_bounds__(64) void k_greedy(
    const float* __restrict__ u, const float* __restrict__ W,
    const float* __restrict__ unif, const double* __restrict__ lseN,
    double* __restrict__ segVal, int* __restrict__ segCol,
    const double* __restrict__ rowSum,
    const unsigned long long* __restrict__ rowKey, int* __restrict__ sel,
    int* __restrict__ selWs) {
  const int lane = threadIdx.x;
  __shared__ double kk[DDIM], sk[DDIM], logLs[DDIM];
  __shared__ int sr[DDIM], sc[DDIM], selL[DDIM];
  __shared__ unsigned int supp[NFEAT / 32];
  for (int i = lane; i < NFEAT / 32; i += 64) supp[i] = 0u;

  double myk[4];
  int myc[4];
#pragma unroll
  for (int i = 0; i < 4; ++i) {
    const int dd = lane + 64 * i;
    const double lL = flog2(rowSum[dd]);
    logLs[dd] = lL;
    const unsigned long long key = rowKey[dd];
    const int col = 0xFFFF - (int)(key & 0xFFFFull);
    const double bv = segVal[(size_t)dd * SEGP + (col >> 5)];  // exact value
    myk[i] = bv - lL;
    myc[i] = col;
    kk[dd] = myk[i];
  }
  __syncthreads();
  // rank sort (descending key, tie -> smaller row)
#pragma unroll
  for (int i = 0; i < 4; ++i) {
    int dd = lane + 64 * i;
    int rk = 0;
#pragma unroll 4
    for (int j = 0; j < DDIM; ++j) {
      double kj = kk[j];
      if (kj > myk[i] || (kj == myk[i] && j < dd)) ++rk;
    }
    sk[rk] = myk[i];
    sr[rk] = dd;
    sc[rk] = myc[i];
  }
  __syncthreads();

  int pos = 0;
  for (int guard = 0; guard < 4 * DDIM && pos < DDIM; ++guard) {
    const int p = pos + lane;
    const bool valid = p < DDIM;
    int r = -1, c = -1000000 - lane;  // unique negatives: no accidental dups
    if (valid) { r = sr[p]; c = sc[p]; }
    bool conf = !valid;
    if (valid) conf = (supp[c >> 5] >> (c & 31)) & 1u;
    bool dup = false;
#pragma unroll
    for (int j = 0; j < 63; ++j) {
      int cj = __shfl(c, j, 64);
      if (j < lane && cj == c) dup = true;
    }
    if (valid && dup) conf = true;
    unsigned long long bm = __ballot(conf);
    int fc = bm ? (__ffsll(bm) - 1) : 64;
    if (lane < fc) {
      selL[r] = c;
      atomicOr(&supp[c >> 5], 1u << (c & 31));
    }
    __syncthreads();
    pos += fc;
    if (fc < 64 && pos < DDIM) {
      const int rr = sr[pos];
      // wave-parallel repair of row rr
      double pbv = -INFINITY;
      int pbc = INT_MAX;
      int stale[10];
      int scnt = 0;
#pragma unroll
      for (int i2 = 0; i2 < 10; ++i2) {
        int s2 = lane + 64 * i2;
        if (s2 < NSEG) {
          double v = segVal[(size_t)rr * SEGP + s2];
          int cc = segCol[(size_t)rr * SEGP + s2];
          if (cc >= 0) {
            if ((supp[cc >> 5] >> (cc & 31)) & 1u) stale[scnt++] = s2;
            else if (v > pbv || (v == pbv && cc < pbc)) { pbv = v; pbc = cc; }
          }
        }
      }
      unsigned long long sm2 = __ballot(scnt > 0);
      for (int g2 = 0; g2 < NSEG + 4 && sm2; ++g2) {
        int src = __ffsll(sm2) - 1;
        int cand = (scnt > 0) ? stale[scnt - 1] : 0;
        int s2 = __shfl(cand, src, 64);
        if (lane == src) --scnt;
        int ccol = s2 * SEGN + lane;
        double zv = -INFINITY;
        if (lane < SEGN && !((supp[ccol >> 5] >> (ccol & 31)) & 1u))
          zv = compute_z2(u, W, unif, lseN, rr, ccol);
        int zc = (zv == -INFINITY) ? INT_MAX : ccol;
#pragma unroll
        for (int off = 32; off > 0; off >>= 1) {
          double ov = __shfl_xor(zv, off, 64);
          int oc = __shfl_xor(zc, off, 64);
          if (ov > zv || (ov == zv && oc < zc)) { zv = ov; zc = oc; }
        }
        if (lane == 0) {
          segVal[(size_t)rr * SEGP + s2] = (zc == INT_MAX) ? -INFINITY : zv;
          segCol[(size_t)rr * SEGP + s2] = (zc == INT_MAX) ? -1 : zc;
        }
        if (zc != INT_MAX && (zv > pbv || (zv == pbv && zc < pbc))) {
          pbv = zv;
          pbc = zc;
        }
        sm2 = __ballot(scnt > 0);
      }
#pragma unroll
      for (int off = 32; off > 0; off >>= 1) {
        double ov = __shfl_xor(pbv, off, 64);
        int oc = __shfl_xor(pbc, off, 64);
        if (ov > pbv || (ov == pbv && oc < pbc)) { pbv = ov; pbc = oc; }
      }
      const double knew = pbv - logLs[rr];
      const int cn = pbc;
      // count entries that must stay ahead of the repaired one
      int cnt = 0;
      for (int q = pos + 1 + lane; q < DDIM; q += 64) {
        double kq = sk[q];
        int rq = sr[q];
        if (kq > knew || (kq == knew && rq < rr)) ++cnt;
      }
#pragma unroll
      for (int off = 32; off > 0; off >>= 1) cnt += __shfl_xor(cnt, off, 64);
      // shift entries pos+1 .. pos+cnt left by one, insert at pos+cnt
      for (int q0 = pos + 1; q0 <= pos + cnt; q0 += 64) {
        int q = q0 + lane;
        double tk = 0.0;
        int tr = 0, tc = 0;
        bool v2 = q <= pos + cnt;
        if (v2) { tk = sk[q]; tr = sr[q]; tc = sc[q]; }
        __syncthreads();
        if (v2) { sk[q - 1] = tk; sr[q - 1] = tr; sc[q - 1] = tc; }
        __syncthreads();
      }
      if (lane == 0) { sk[pos + cnt] = knew; sr[pos + cnt] = rr; sc[pos + cnt] = cn; }
      __syncthreads();
    }
  }
#pragma unroll
  for (int i = 0; i < 4; ++i) {
    const int v = selL[lane + 64 * i];
    sel[lane + 64 * i] = v;
    if (selWs) selWs[lane + 64 * i] = v;
  }
}

// ---------------------------------------------------------------------------
// K4a (ws path): all 4096 rows in one kernel; sel lives in d_ws, so block 0
// may safely overwrite out row 0.
// ---------------------------------------------------------------------------
__global__ __launch_bounds__(256) void k_gather_all(
    const float* __restrict__ X, const int* __restrict__ selWs, float* out) {
  const int dd = threadIdx.x;
  const size_t b = (size_t)blockIdx.x;
  out[b * DDIM + dd] = X[b * NFEAT + selWs[dd]];
}

// K4b/K5 (fallback path, sel bit-stashed in out row 0).
__global__ __launch_bounds__(256) void k_gather(const float* __restrict__ X,
                                                float* out) {
  const int dd = threadIdx.x;
  const size_t b = (size_t)blockIdx.x + 1;
  const int y = __float_as_int(out[dd]);
  out[b * DDIM + dd] = X[b * NFEAT + y];
}

__global__ __launch_bounds__(256) void k_row0(const float* __restrict__ X,
                                              float* out) {
  const int dd = threadIdx.x;
  const int y = __float_as_int(out[dd]);
  const float v = X[y];
  out[dd] = v;
}

extern "C" void kernel_launch(void* const* d_in, const int* in_sizes, int n_in,
                              void* d_out, int out_size, void* d_ws,
                              size_t ws_size, hipStream_t stream) {
  (void)in_sizes; (void)n_in; (void)out_size;
  const float* X = (const float*)d_in[0];
  const float* u = (const float*)d_in[1];
  const float* W = (const float*)d_in[2];
  const float* unif = (const float*)d_in[3];

  // Scratch lives inside d_out (4 MB): rows >= 1 are dead until the gather.
  char* ob = (char*)d_out;
  int* sel = (int*)ob;                                      // [0, 1024)
  double* lseN = (double*)(ob + 1024);                      // 160000 -> 161024
  double* rowSum = (double*)(ob + 161024);                  // 2048 -> 163072
  unsigned long long* rowKey = (unsigned long long*)(ob + 163072);  // 2048 -> 165120
  double* segVal = (double*)(ob + 165120);                  // 256*640*8 -> 1475840
  int* segCol = (int*)(ob + 1475840);                       // 655360 -> 2131200 (<4MB)

  const bool use_ws = (d_ws != nullptr) && (ws_size >= 4096);
  int* selWs = use_ws ? (int*)d_ws : nullptr;

  k_init<<<1, 256, 0, stream>>>(rowSum, rowKey);
  k_seg<<<NSEG, 256, 0, stream>>>(u, W, unif, lseN, segVal, segCol, rowSum,
                                  rowKey);
  k_greedy<<<1, 64, 0, stream>>>(u, W, unif, lseN, segVal, segCol, rowSum,
                                 rowKey, sel, selWs);
  if (use_ws) {
    k_gather_all<<<4096, 256, 0, stream>>>(X, selWs, (float*)d_out);
  } else {
    k_gather<<<4095, 256, 0, stream>>>(X, (float*)d_out);
    k_row0<<<1, 256, 0, stream>>>(X, (float*)d_out);
  }
}